// Round 6
// baseline (125.280 us; speedup 1.0000x reference)
//
#include <hip/hip_runtime.h>
#include <hip/hip_bf16.h>

// Decoder_bipartite: out[e] = sigmoid( relu( [z_src[row[e]] ; z_dst[col[e]]] @ W1^T + b1 ) @ W2^T + b2 )
// R6: R5 + conflict-free (transposed) LDS b1/W2 table + 2 edges per thread (deeper MLP,
//     halved LDS reads per edge). u_src/u_dst precomputed in bf16 by prep_gemm (pair-permuted).

#define H 128
#define K2 256

typedef __bf16 bf16x8 __attribute__((ext_vector_type(8)));
typedef float  f32x4  __attribute__((ext_vector_type(4)));

__device__ __forceinline__ bf16x8 cvt8(const float4 a, const float4 b) {
    bf16x8 r;
    r[0] = (__bf16)a.x; r[1] = (__bf16)a.y; r[2] = (__bf16)a.z; r[3] = (__bf16)a.w;
    r[4] = (__bf16)b.x; r[5] = (__bf16)b.y; r[6] = (__bf16)b.z; r[7] = (__bf16)b.w;
    return r;
}

// ---------------- prep: u = z @ W1half^T  (bf16 out, pair-permuted cols) ----------------
// u row storage (64 u32 words): word w = np*16+c holds cols j=(2np)*16+c (lo), (2np+1)*16+c (hi).
__global__ __launch_bounds__(256, 2)
void prep_gemm(const float* __restrict__ zsrc, const float* __restrict__ zdst,
               const float* __restrict__ W1,
               __bf16* __restrict__ usrc, __bf16* __restrict__ udst,
               int Msrc, int Mdst, int nsrc_tiles) {
    __shared__ __bf16 sB[32 * 64 * 8];   // 32 KB: [slot=kb*8+nt][lane][8]

    const int tid  = threadIdx.x;
    const int lane = tid & 63;
    const int wave = tid >> 6;
    const int q    = lane >> 4;

    const int  bt     = blockIdx.x;
    const bool is_src = bt < nsrc_tiles;
    const float* z    = is_src ? zsrc : zdst;
    __bf16*    u      = is_src ? usrc : udst;
    const int  M      = is_src ? Msrc : Mdst;
    const int  tile   = is_src ? bt : bt - nsrc_tiles;
    const int  hoff   = is_src ? 0 : H;

    #pragma unroll
    for (int i = 0; i < 8; ++i) {
        int c    = tid + 256 * i;          // 0..2047
        int cl   = c & 63;
        int slot = c >> 6;                 // kb*8+nt
        int kb   = slot >> 3, nt = slot & 7;
        int n    = nt * 16 + (cl & 15);
        int k0   = kb * 32 + ((cl >> 4) << 3);
        const float4* wp = reinterpret_cast<const float4*>(W1 + (size_t)n * K2 + hoff + k0);
        *reinterpret_cast<bf16x8*>(&sB[(size_t)c * 8]) = cvt8(wp[0], wp[1]);
    }
    __syncthreads();

    const int rbase = tile * 128 + wave * 32;
    int m0 = rbase + (lane & 15);
    int m1 = m0 + 16;
    int m0c = m0 < M ? m0 : M - 1;
    int m1c = m1 < M ? m1 : M - 1;
    const float* a0 = z + (size_t)m0c * H;
    const float* a1 = z + (size_t)m1c * H;

    bf16x8 A0[4], A1[4];
    #pragma unroll
    for (int kb = 0; kb < 4; ++kb) {
        const float4* q0 = reinterpret_cast<const float4*>(a0 + kb * 32 + q * 8);
        const float4* q1 = reinterpret_cast<const float4*>(a1 + kb * 32 + q * 8);
        A0[kb] = cvt8(q0[0], q0[1]);
        A1[kb] = cvt8(q1[0], q1[1]);
    }

    f32x4 zero = {0.f, 0.f, 0.f, 0.f};
    f32x4 acc[2][8];
    #pragma unroll
    for (int mt = 0; mt < 2; ++mt)
        #pragma unroll
        for (int nt = 0; nt < 8; ++nt) acc[mt][nt] = zero;

    #pragma unroll
    for (int kb = 0; kb < 4; ++kb)
        #pragma unroll
        for (int nt = 0; nt < 8; ++nt) {
            bf16x8 bfr = *reinterpret_cast<const bf16x8*>(&sB[(size_t)((kb * 8 + nt) * 64 + lane) * 8]);
            acc[0][nt] = __builtin_amdgcn_mfma_f32_16x16x32_bf16(A0[kb], bfr, acc[0][nt], 0, 0, 0);
            acc[1][nt] = __builtin_amdgcn_mfma_f32_16x16x32_bf16(A1[kb], bfr, acc[1][nt], 0, 0, 0);
        }

    #pragma unroll
    for (int mt = 0; mt < 2; ++mt)
        #pragma unroll
        for (int r = 0; r < 4; ++r) {
            int rowo = rbase + mt * 16 + q * 4 + r;
            if (rowo < M) {
                unsigned* urow = reinterpret_cast<unsigned*>(u + (size_t)rowo * H);
                #pragma unroll
                for (int np = 0; np < 4; ++np) {
                    union { __bf16 h[2]; unsigned w; } pk;
                    pk.h[0] = (__bf16)acc[mt][2 * np][r];
                    pk.h[1] = (__bf16)acc[mt][2 * np + 1][r];
                    urow[np * 16 + (lane & 15)] = pk.w;
                }
            }
        }
}

// ---------------- edge kernel: quad-per-edge gather, 2 edges/thread ----------------
__global__ __launch_bounds__(256, 4)
void edge_kernel(const __bf16* __restrict__ usrc, const __bf16* __restrict__ udst,
                 const int* __restrict__ row, const int* __restrict__ col,
                 const float* __restrict__ b1, const float* __restrict__ W2,
                 const float* __restrict__ b2, float* __restrict__ out, int E) {
    // Transposed table: physical p = idx*4 + q  (idx = t*4+d), logical word w = q*16 + idx.
    // Quad lanes (q=0..3) read words 4 apart -> distinct banks; same-q lanes broadcast.
    __shared__ float4 sbwT[64];
    const int tid = threadIdx.x;
    if (tid < 64) {
        int idx = tid >> 2, qq = tid & 3;
        int w  = qq * 16 + idx;
        int np = w >> 4, c = w & 15;
        int j0 = (2 * np) * 16 + c;
        int j1 = (2 * np + 1) * 16 + c;
        sbwT[tid] = make_float4(b1[j0], W2[j0], b1[j1], W2[j1]);
    }
    __syncthreads();

    const int q    = tid & 3;
    const int slot = tid >> 2;                   // 0..63
    const int e0   = blockIdx.x * 128 + slot;    // 128 edges per block
    const int e1   = e0 + 64;
    const int e0c  = e0 < E ? e0 : E - 1;
    const int e1c  = e1 < E ? e1 : E - 1;

    const char* ps0 = reinterpret_cast<const char*>(usrc + (size_t)row[e0c] * H) + q * 64;
    const char* pd0 = reinterpret_cast<const char*>(udst + (size_t)col[e0c] * H) + q * 64;
    const char* ps1 = reinterpret_cast<const char*>(usrc + (size_t)row[e1c] * H) + q * 64;
    const char* pd1 = reinterpret_cast<const char*>(udst + (size_t)col[e1c] * H) + q * 64;

    // 16 independent 16-B loads, all in flight before first use
    bf16x8 sa0[4], sc0[4], sa1[4], sc1[4];
    #pragma unroll
    for (int t = 0; t < 4; ++t) sa0[t] = *reinterpret_cast<const bf16x8*>(ps0 + t * 16);
    #pragma unroll
    for (int t = 0; t < 4; ++t) sc0[t] = *reinterpret_cast<const bf16x8*>(pd0 + t * 16);
    #pragma unroll
    for (int t = 0; t < 4; ++t) sa1[t] = *reinterpret_cast<const bf16x8*>(ps1 + t * 16);
    #pragma unroll
    for (int t = 0; t < 4; ++t) sc1[t] = *reinterpret_cast<const bf16x8*>(pd1 + t * 16);

    float acc0 = 0.f, acc1 = 0.f;
    #pragma unroll
    for (int t = 0; t < 4; ++t) {
        #pragma unroll
        for (int d = 0; d < 4; ++d) {
            float4 v = sbwT[(t * 4 + d) * 4 + q];
            float h00 = fmaxf((float)sa0[t][2 * d]     + (float)sc0[t][2 * d]     + v.x, 0.f);
            acc0 = fmaf(h00, v.y, acc0);
            float h01 = fmaxf((float)sa0[t][2 * d + 1] + (float)sc0[t][2 * d + 1] + v.z, 0.f);
            acc0 = fmaf(h01, v.w, acc0);
            float h10 = fmaxf((float)sa1[t][2 * d]     + (float)sc1[t][2 * d]     + v.x, 0.f);
            acc1 = fmaf(h10, v.y, acc1);
            float h11 = fmaxf((float)sa1[t][2 * d + 1] + (float)sc1[t][2 * d + 1] + v.z, 0.f);
            acc1 = fmaf(h11, v.w, acc1);
        }
    }
    acc0 += __shfl_xor(acc0, 1);
    acc0 += __shfl_xor(acc0, 2);
    acc1 += __shfl_xor(acc1, 1);
    acc1 += __shfl_xor(acc1, 2);
    if (q == 0) {
        const float bias2 = b2[0];
        if (e0 < E) out[e0] = 1.f / (1.f + __expf(-(acc0 + bias2)));
        if (e1 < E) out[e1] = 1.f / (1.f + __expf(-(acc1 + bias2)));
    }
}

// ---------------- fallback (ws too small): direct MFMA kernel (R3 structure) ----------------
__global__ __launch_bounds__(256, 2)
void decoder_f32(const float* __restrict__ zsrc, const float* __restrict__ zdst,
                 const int* __restrict__ row, const int* __restrict__ col,
                 const float* __restrict__ W1, const float* __restrict__ b1,
                 const float* __restrict__ W2, const float* __restrict__ b2,
                 float* __restrict__ out, int E, int ntiles) {
    __shared__ __bf16 sB[64 * 64 * 8];
    const int tid = threadIdx.x, lane = tid & 63, wave = tid >> 6, q = lane >> 4;
    #pragma unroll
    for (int i = 0; i < 16; ++i) {
        int c = tid + 256 * i, cl = c & 63, slot = c >> 6;
        int kb = slot >> 3, nt = slot & 7;
        int n = nt * 16 + (cl & 15);
        int k0 = kb * 32 + ((cl >> 4) << 3);
        const float4* wp = reinterpret_cast<const float4*>(W1 + (size_t)n * K2 + k0);
        *reinterpret_cast<bf16x8*>(&sB[(size_t)c * 8]) = cvt8(wp[0], wp[1]);
    }
    float b1v[8], w2v[8];
    #pragma unroll
    for (int nt = 0; nt < 8; ++nt) { b1v[nt] = b1[nt * 16 + (lane & 15)]; w2v[nt] = W2[nt * 16 + (lane & 15)]; }
    const float bias2 = b2[0];
    __syncthreads();
    for (int tile = blockIdx.x; tile < ntiles; tile += gridDim.x) {
        const int rbase = tile * 128 + wave * 32;
        int e0 = rbase + (lane & 15), e1 = e0 + 16;
        int e0c = e0 < E ? e0 : E - 1, e1c = e1 < E ? e1 : E - 1;
        const float* a0s = zsrc + (size_t)row[e0c] * H;
        const float* a1s = zsrc + (size_t)row[e1c] * H;
        const float* a0d = zdst + (size_t)col[e0c] * H;
        const float* a1d = zdst + (size_t)col[e1c] * H;
        f32x4 zero = {0.f, 0.f, 0.f, 0.f};
        f32x4 acc[2][8];
        #pragma unroll
        for (int mt = 0; mt < 2; ++mt)
            #pragma unroll
            for (int nt = 0; nt < 8; ++nt) acc[mt][nt] = zero;
        #pragma unroll
        for (int kb = 0; kb < 8; ++kb) {
            const float* p0 = (kb < 4) ? a0s : a0d;
            const float* p1 = (kb < 4) ? a1s : a1d;
            const int ko = ((kb & 3) << 5) + (q << 3);
            const float4* q0 = reinterpret_cast<const float4*>(p0 + ko);
            const float4* q1 = reinterpret_cast<const float4*>(p1 + ko);
            bf16x8 afr0 = cvt8(q0[0], q0[1]);
            bf16x8 afr1 = cvt8(q1[0], q1[1]);
            #pragma unroll
            for (int nt = 0; nt < 8; ++nt) {
                bf16x8 bfr = *reinterpret_cast<const bf16x8*>(&sB[(size_t)((kb * 8 + nt) * 64 + lane) * 8]);
                acc[0][nt] = __builtin_amdgcn_mfma_f32_16x16x32_bf16(afr0, bfr, acc[0][nt], 0, 0, 0);
                acc[1][nt] = __builtin_amdgcn_mfma_f32_16x16x32_bf16(afr1, bfr, acc[1][nt], 0, 0, 0);
            }
        }
        #pragma unroll
        for (int mt = 0; mt < 2; ++mt)
            #pragma unroll
            for (int r = 0; r < 4; ++r) {
                float p = 0.f;
                #pragma unroll
                for (int nt = 0; nt < 8; ++nt) {
                    float h = acc[mt][nt][r] + b1v[nt];
                    h = h > 0.f ? h : 0.f;
                    p += h * w2v[nt];
                }
                p += __shfl_xor(p, 1); p += __shfl_xor(p, 2);
                p += __shfl_xor(p, 4); p += __shfl_xor(p, 8);
                int e = rbase + mt * 16 + (q << 2) + r;
                if ((lane & 15) == 0 && e < E)
                    out[e] = 1.f / (1.f + __expf(-(p + bias2)));
            }
    }
}

extern "C" void kernel_launch(void* const* d_in, const int* in_sizes, int n_in,
                              void* d_out, int out_size, void* d_ws, size_t ws_size,
                              hipStream_t stream) {
    const float* zsrc = (const float*)d_in[0];
    const float* zdst = (const float*)d_in[1];
    const int*   eli  = (const int*)d_in[2];   // [2,E] flat: row then col
    const float* W1   = (const float*)d_in[3];
    const float* b1   = (const float*)d_in[4];
    const float* W2   = (const float*)d_in[5];
    const float* b2   = (const float*)d_in[6];
    float* out = (float*)d_out;

    const int E    = in_sizes[2] / 2;
    const int Msrc = in_sizes[0] / H;
    const int Mdst = in_sizes[1] / H;

    const size_t need = ((size_t)Msrc + Mdst) * H * sizeof(__bf16);
    if (ws_size >= need) {
        __bf16* usrc = (__bf16*)d_ws;
        __bf16* udst = usrc + (size_t)Msrc * H;
        const int nsrc_tiles = (Msrc + 127) / 128;
        const int ndst_tiles = (Mdst + 127) / 128;
        prep_gemm<<<nsrc_tiles + ndst_tiles, 256, 0, stream>>>(zsrc, zdst, W1, usrc, udst,
                                                               Msrc, Mdst, nsrc_tiles);
        edge_kernel<<<(E + 127) / 128, 256, 0, stream>>>(usrc, udst, eli, eli + E,
                                                         b1, W2, b2, out, E);
    } else {
        const int ntiles = (E + 127) / 128;
        const int grid = ntiles < 1024 ? ntiles : 1024;
        decoder_f32<<<grid, 256, 0, stream>>>(zsrc, zdst, eli, eli + E,
                                              W1, b1, W2, b2, out, E, ntiles);
    }
}

// Round 7
// 94.805 us; speedup vs baseline: 1.3214x; 1.3214x over previous
//
#include <hip/hip_runtime.h>
#include <hip/hip_bf16.h>

// Decoder_bipartite: out[e] = sigmoid( relu( [z_src[row[e]] ; z_dst[col[e]]] @ W1^T + b1 ) @ W2^T + b2 )
// R7: R5 structure (1 edge per quad-thread, 8 hoisted 16B loads) + conflict-free transposed
//     LDS b1/W2 table + non-temporal edge-list loads / out stores.
//     u_src=z_src@W1s^T, u_dst=z_dst@W1d^T precomputed in bf16 (pair-permuted rows).

#define H 128
#define K2 256

typedef __bf16 bf16x8 __attribute__((ext_vector_type(8)));
typedef float  f32x4  __attribute__((ext_vector_type(4)));

__device__ __forceinline__ bf16x8 cvt8(const float4 a, const float4 b) {
    bf16x8 r;
    r[0] = (__bf16)a.x; r[1] = (__bf16)a.y; r[2] = (__bf16)a.z; r[3] = (__bf16)a.w;
    r[4] = (__bf16)b.x; r[5] = (__bf16)b.y; r[6] = (__bf16)b.z; r[7] = (__bf16)b.w;
    return r;
}

// ---------------- prep: u = z @ W1half^T  (bf16 out, pair-permuted cols) ----------------
// u row storage (64 u32 words): word w = np*16+c holds cols j=(2np)*16+c (lo), (2np+1)*16+c (hi).
__global__ __launch_bounds__(256, 2)
void prep_gemm(const float* __restrict__ zsrc, const float* __restrict__ zdst,
               const float* __restrict__ W1,
               __bf16* __restrict__ usrc, __bf16* __restrict__ udst,
               int Msrc, int Mdst, int nsrc_tiles) {
    __shared__ __bf16 sB[32 * 64 * 8];   // 32 KB: [slot=kb*8+nt][lane][8]

    const int tid  = threadIdx.x;
    const int lane = tid & 63;
    const int wave = tid >> 6;
    const int q    = lane >> 4;

    const int  bt     = blockIdx.x;
    const bool is_src = bt < nsrc_tiles;
    const float* z    = is_src ? zsrc : zdst;
    __bf16*    u      = is_src ? usrc : udst;
    const int  M      = is_src ? Msrc : Mdst;
    const int  tile   = is_src ? bt : bt - nsrc_tiles;
    const int  hoff   = is_src ? 0 : H;

    #pragma unroll
    for (int i = 0; i < 8; ++i) {
        int c    = tid + 256 * i;          // 0..2047
        int cl   = c & 63;
        int slot = c >> 6;                 // kb*8+nt
        int kb   = slot >> 3, nt = slot & 7;
        int n    = nt * 16 + (cl & 15);
        int k0   = kb * 32 + ((cl >> 4) << 3);
        const float4* wp = reinterpret_cast<const float4*>(W1 + (size_t)n * K2 + hoff + k0);
        *reinterpret_cast<bf16x8*>(&sB[(size_t)c * 8]) = cvt8(wp[0], wp[1]);
    }
    __syncthreads();

    const int rbase = tile * 128 + wave * 32;
    int m0 = rbase + (lane & 15);
    int m1 = m0 + 16;
    int m0c = m0 < M ? m0 : M - 1;
    int m1c = m1 < M ? m1 : M - 1;
    const float* a0 = z + (size_t)m0c * H;
    const float* a1 = z + (size_t)m1c * H;

    bf16x8 A0[4], A1[4];
    #pragma unroll
    for (int kb = 0; kb < 4; ++kb) {
        const float4* q0 = reinterpret_cast<const float4*>(a0 + kb * 32 + q * 8);
        const float4* q1 = reinterpret_cast<const float4*>(a1 + kb * 32 + q * 8);
        A0[kb] = cvt8(q0[0], q0[1]);
        A1[kb] = cvt8(q1[0], q1[1]);
    }

    f32x4 zero = {0.f, 0.f, 0.f, 0.f};
    f32x4 acc[2][8];
    #pragma unroll
    for (int mt = 0; mt < 2; ++mt)
        #pragma unroll
        for (int nt = 0; nt < 8; ++nt) acc[mt][nt] = zero;

    #pragma unroll
    for (int kb = 0; kb < 4; ++kb)
        #pragma unroll
        for (int nt = 0; nt < 8; ++nt) {
            bf16x8 bfr = *reinterpret_cast<const bf16x8*>(&sB[(size_t)((kb * 8 + nt) * 64 + lane) * 8]);
            acc[0][nt] = __builtin_amdgcn_mfma_f32_16x16x32_bf16(A0[kb], bfr, acc[0][nt], 0, 0, 0);
            acc[1][nt] = __builtin_amdgcn_mfma_f32_16x16x32_bf16(A1[kb], bfr, acc[1][nt], 0, 0, 0);
        }

    #pragma unroll
    for (int mt = 0; mt < 2; ++mt)
        #pragma unroll
        for (int r = 0; r < 4; ++r) {
            int rowo = rbase + mt * 16 + q * 4 + r;
            if (rowo < M) {
                unsigned* urow = reinterpret_cast<unsigned*>(u + (size_t)rowo * H);
                #pragma unroll
                for (int np = 0; np < 4; ++np) {
                    union { __bf16 h[2]; unsigned w; } pk;
                    pk.h[0] = (__bf16)acc[mt][2 * np][r];
                    pk.h[1] = (__bf16)acc[mt][2 * np + 1][r];
                    urow[np * 16 + (lane & 15)] = pk.w;
                }
            }
        }
}

// ---------------- edge kernel: quad-per-edge gather + relu + dot ----------------
__global__ __launch_bounds__(256, 4)
void edge_kernel(const __bf16* __restrict__ usrc, const __bf16* __restrict__ udst,
                 const int* __restrict__ row, const int* __restrict__ col,
                 const float* __restrict__ b1, const float* __restrict__ W2,
                 const float* __restrict__ b2, float* __restrict__ out, int E) {
    // Transposed table: physical p = idx*4 + q  (idx = t*4+d), logical word w = q*16 + idx.
    // Quad lanes (q=0..3) read consecutive float4s -> distinct banks; same-q lanes broadcast.
    __shared__ float4 sbwT[64];
    const int tid = threadIdx.x;
    if (tid < 64) {
        int idx = tid >> 2, qq = tid & 3;
        int w  = qq * 16 + idx;
        int np = w >> 4, c = w & 15;
        int j0 = (2 * np) * 16 + c;
        int j1 = (2 * np + 1) * 16 + c;
        sbwT[tid] = make_float4(b1[j0], W2[j0], b1[j1], W2[j1]);
    }
    __syncthreads();

    const int q = tid & 3;                      // lane-in-quad
    const int e = blockIdx.x * 64 + (tid >> 2); // 64 edges per 256-thr block
    if (e >= E) return;                         // uniform within a quad

    const int re = __builtin_nontemporal_load(&row[e]);
    const int ce = __builtin_nontemporal_load(&col[e]);
    const char* ps = reinterpret_cast<const char*>(usrc + (size_t)re * H) + q * 64;
    const char* pd = reinterpret_cast<const char*>(udst + (size_t)ce * H) + q * 64;

    // 8 independent 16-B loads -> all in flight before first use
    bf16x8 a[4], b[4];
    #pragma unroll
    for (int t = 0; t < 4; ++t) a[t] = *reinterpret_cast<const bf16x8*>(ps + t * 16);
    #pragma unroll
    for (int t = 0; t < 4; ++t) b[t] = *reinterpret_cast<const bf16x8*>(pd + t * 16);

    float acc = 0.f;
    #pragma unroll
    for (int t = 0; t < 4; ++t) {
        #pragma unroll
        for (int d = 0; d < 4; ++d) {
            float4 v = sbwT[(t * 4 + d) * 4 + q];
            float h0 = fmaxf((float)a[t][2 * d]     + (float)b[t][2 * d]     + v.x, 0.f);
            acc = fmaf(h0, v.y, acc);
            float h1 = fmaxf((float)a[t][2 * d + 1] + (float)b[t][2 * d + 1] + v.z, 0.f);
            acc = fmaf(h1, v.w, acc);
        }
    }
    acc += __shfl_xor(acc, 1);
    acc += __shfl_xor(acc, 2);
    if (q == 0) {
        float r = 1.f / (1.f + __expf(-(acc + b2[0])));
        __builtin_nontemporal_store(r, &out[e]);
    }
}

// ---------------- fallback (ws too small): direct MFMA kernel (R3 structure) ----------------
__global__ __launch_bounds__(256, 2)
void decoder_f32(const float* __restrict__ zsrc, const float* __restrict__ zdst,
                 const int* __restrict__ row, const int* __restrict__ col,
                 const float* __restrict__ W1, const float* __restrict__ b1,
                 const float* __restrict__ W2, const float* __restrict__ b2,
                 float* __restrict__ out, int E, int ntiles) {
    __shared__ __bf16 sB[64 * 64 * 8];
    const int tid = threadIdx.x, lane = tid & 63, wave = tid >> 6, q = lane >> 4;
    #pragma unroll
    for (int i = 0; i < 16; ++i) {
        int c = tid + 256 * i, cl = c & 63, slot = c >> 6;
        int kb = slot >> 3, nt = slot & 7;
        int n = nt * 16 + (cl & 15);
        int k0 = kb * 32 + ((cl >> 4) << 3);
        const float4* wp = reinterpret_cast<const float4*>(W1 + (size_t)n * K2 + k0);
        *reinterpret_cast<bf16x8*>(&sB[(size_t)c * 8]) = cvt8(wp[0], wp[1]);
    }
    float b1v[8], w2v[8];
    #pragma unroll
    for (int nt = 0; nt < 8; ++nt) { b1v[nt] = b1[nt * 16 + (lane & 15)]; w2v[nt] = W2[nt * 16 + (lane & 15)]; }
    const float bias2 = b2[0];
    __syncthreads();
    for (int tile = blockIdx.x; tile < ntiles; tile += gridDim.x) {
        const int rbase = tile * 128 + wave * 32;
        int e0 = rbase + (lane & 15), e1 = e0 + 16;
        int e0c = e0 < E ? e0 : E - 1, e1c = e1 < E ? e1 : E - 1;
        const float* a0s = zsrc + (size_t)row[e0c] * H;
        const float* a1s = zsrc + (size_t)row[e1c] * H;
        const float* a0d = zdst + (size_t)col[e0c] * H;
        const float* a1d = zdst + (size_t)col[e1c] * H;
        f32x4 zero = {0.f, 0.f, 0.f, 0.f};
        f32x4 acc[2][8];
        #pragma unroll
        for (int mt = 0; mt < 2; ++mt)
            #pragma unroll
            for (int nt = 0; nt < 8; ++nt) acc[mt][nt] = zero;
        #pragma unroll
        for (int kb = 0; kb < 8; ++kb) {
            const float* p0 = (kb < 4) ? a0s : a0d;
            const float* p1 = (kb < 4) ? a1s : a1d;
            const int ko = ((kb & 3) << 5) + (q << 3);
            const float4* q0 = reinterpret_cast<const float4*>(p0 + ko);
            const float4* q1 = reinterpret_cast<const float4*>(p1 + ko);
            bf16x8 afr0 = cvt8(q0[0], q0[1]);
            bf16x8 afr1 = cvt8(q1[0], q1[1]);
            #pragma unroll
            for (int nt = 0; nt < 8; ++nt) {
                bf16x8 bfr = *reinterpret_cast<const bf16x8*>(&sB[(size_t)((kb * 8 + nt) * 64 + lane) * 8]);
                acc[0][nt] = __builtin_amdgcn_mfma_f32_16x16x32_bf16(afr0, bfr, acc[0][nt], 0, 0, 0);
                acc[1][nt] = __builtin_amdgcn_mfma_f32_16x16x32_bf16(afr1, bfr, acc[1][nt], 0, 0, 0);
            }
        }
        #pragma unroll
        for (int mt = 0; mt < 2; ++mt)
            #pragma unroll
            for (int r = 0; r < 4; ++r) {
                float p = 0.f;
                #pragma unroll
                for (int nt = 0; nt < 8; ++nt) {
                    float h = acc[mt][nt][r] + b1v[nt];
                    h = h > 0.f ? h : 0.f;
                    p += h * w2v[nt];
                }
                p += __shfl_xor(p, 1); p += __shfl_xor(p, 2);
                p += __shfl_xor(p, 4); p += __shfl_xor(p, 8);
                int e = rbase + mt * 16 + (q << 2) + r;
                if ((lane & 15) == 0 && e < E)
                    out[e] = 1.f / (1.f + __expf(-(p + bias2)));
            }
    }
}

extern "C" void kernel_launch(void* const* d_in, const int* in_sizes, int n_in,
                              void* d_out, int out_size, void* d_ws, size_t ws_size,
                              hipStream_t stream) {
    const float* zsrc = (const float*)d_in[0];
    const float* zdst = (const float*)d_in[1];
    const int*   eli  = (const int*)d_in[2];   // [2,E] flat: row then col
    const float* W1   = (const float*)d_in[3];
    const float* b1   = (const float*)d_in[4];
    const float* W2   = (const float*)d_in[5];
    const float* b2   = (const float*)d_in[6];
    float* out = (float*)d_out;

    const int E    = in_sizes[2] / 2;
    const int Msrc = in_sizes[0] / H;
    const int Mdst = in_sizes[1] / H;

    const size_t need = ((size_t)Msrc + Mdst) * H * sizeof(__bf16);
    if (ws_size >= need) {
        __bf16* usrc = (__bf16*)d_ws;
        __bf16* udst = usrc + (size_t)Msrc * H;
        const int nsrc_tiles = (Msrc + 127) / 128;
        const int ndst_tiles = (Mdst + 127) / 128;
        prep_gemm<<<nsrc_tiles + ndst_tiles, 256, 0, stream>>>(zsrc, zdst, W1, usrc, udst,
                                                               Msrc, Mdst, nsrc_tiles);
        edge_kernel<<<(E + 63) / 64, 256, 0, stream>>>(usrc, udst, eli, eli + E,
                                                       b1, W2, b2, out, E);
    } else {
        const int ntiles = (E + 127) / 128;
        const int grid = ntiles < 1024 ? ntiles : 1024;
        decoder_f32<<<grid, 256, 0, stream>>>(zsrc, zdst, eli, eli + E,
                                              W1, b1, W2, b2, out, E, ntiles);
    }
}